// Round 1
// baseline (95.913 us; speedup 1.0000x reference)
//
#include <hip/hip_runtime.h>

#define C_DIM 2048
#define T_TOKENS 4096

// Kernel 1: scores[n] = dot(hidden[n, :], W) + b0, one wave per token.
__global__ __launch_bounds__(256) void score_kernel(
    const float* __restrict__ hidden, const float* __restrict__ W,
    const float* __restrict__ bptr, float* __restrict__ scores, int n_tokens) {
  int wave = (int)((blockIdx.x * blockDim.x + threadIdx.x) >> 6);
  int lane = threadIdx.x & 63;
  if (wave >= n_tokens) return;
  const float* row = hidden + (size_t)wave * C_DIM;
  double acc = 0.0;
#pragma unroll
  for (int it = 0; it < C_DIM / (64 * 4); ++it) {
    int c = it * 256 + lane * 4;
    float4 h = *reinterpret_cast<const float4*>(row + c);
    float4 w = *reinterpret_cast<const float4*>(W + c);
    acc += (double)h.x * (double)w.x;
    acc += (double)h.y * (double)w.y;
    acc += (double)h.z * (double)w.z;
    acc += (double)h.w * (double)w.w;
  }
  // wave-64 butterfly reduce (double)
  for (int o = 32; o; o >>= 1) acc += __shfl_xor(acc, o);
  if (lane == 0) scores[wave] = (float)(acc + (double)bptr[0]);
}

// Kernel 2: per-batch variable-k top-k mask via radix bit-descent selection.
// Mask semantics exactly match argsort(argsort) rank: token kept iff
// score strictly above the k-th largest, or equal to it with stable
// (smaller-index-first) tie rank below the remaining quota.
__global__ __launch_bounds__(256) void topk_mask_kernel(
    const float* __restrict__ keep_ratio, const float* __restrict__ scores_all,
    float* __restrict__ mask) {
  const int b = blockIdx.x;
  const float* scores = scores_all + (size_t)b * T_TOKENS;
  __shared__ unsigned int s_keys[T_TOKENS];  // 16 KiB
  __shared__ int s_red[4];
  const int tid = threadIdx.x;

  // k = max(1, trunc(clip(kr, 0.1, 1.0) * T)); fp32 *4096 is exact.
  float kf = keep_ratio[b];
  kf = fminf(fmaxf(kf, 0.1f), 1.0f);
  int k = (int)(kf * (float)T_TOKENS);
  if (k < 1) k = 1;

  // Load scores -> order-preserving uint keys (ascending float order).
  unsigned int key[16];
#pragma unroll
  for (int i = 0; i < 16; ++i) {
    int t = tid + i * 256;
    float s = scores[t];
    if (s == 0.0f) s = 0.0f;  // canonicalize -0.0
    unsigned int u = __float_as_uint(s);
    unsigned int kk = (u & 0x80000000u) ? ~u : (u | 0x80000000u);
    key[i] = kk;
    s_keys[t] = kk;
  }
  __syncthreads();

  // Bit-descent: find max x such that count(key >= x) >= k  ==  k-th largest.
  unsigned int prefix = 0u;
  for (int bit = 31; bit >= 0; --bit) {
    unsigned int test = prefix | (1u << bit);
    int c = 0;
#pragma unroll
    for (int i = 0; i < 16; ++i) c += (key[i] >= test) ? 1 : 0;
    for (int o = 32; o; o >>= 1) c += __shfl_xor(c, o);
    if ((tid & 63) == 0) s_red[tid >> 6] = c;
    __syncthreads();
    c = s_red[0] + s_red[1] + s_red[2] + s_red[3];
    __syncthreads();
    if (c >= k) prefix = test;
  }

  // Count strictly-greater; remaining quota goes to ties by index order.
  int cg = 0;
#pragma unroll
  for (int i = 0; i < 16; ++i) cg += (key[i] > prefix) ? 1 : 0;
  for (int o = 32; o; o >>= 1) cg += __shfl_xor(cg, o);
  if ((tid & 63) == 0) s_red[tid >> 6] = cg;
  __syncthreads();
  cg = s_red[0] + s_red[1] + s_red[2] + s_red[3];
  __syncthreads();
  const int n_eq_keep = k - cg;

#pragma unroll
  for (int i = 0; i < 16; ++i) {
    int t = tid + i * 256;
    unsigned int kk = key[i];
    float m;
    if (kk > prefix) {
      m = 1.0f;
    } else if (kk == prefix) {
      int r = 0;  // stable tie-break: equals with smaller index rank first
      for (int j = 0; j < t; ++j) r += (s_keys[j] == prefix) ? 1 : 0;
      m = (r < n_eq_keep) ? 1.0f : 0.0f;
    } else {
      m = 0.0f;
    }
    mask[(size_t)b * T_TOKENS + t] = m;
  }
}

extern "C" void kernel_launch(void* const* d_in, const int* in_sizes, int n_in,
                              void* d_out, int out_size, void* d_ws, size_t ws_size,
                              hipStream_t stream) {
  const float* hidden = (const float*)d_in[0];
  const float* keep_ratio = (const float*)d_in[1];
  const float* W = (const float*)d_in[2];
  const float* bptr = (const float*)d_in[3];

  const int B = in_sizes[1];
  const int n_tokens = in_sizes[0] / C_DIM;  // B*T = 32768

  float* out = (float*)d_out;
  float* mask = out;                       // output 0: [B, T] mask as 0/1 float
  float* scores = out + (size_t)n_tokens;  // output 1: [B, T] fp32 scores

  // 4 waves per block, one token per wave.
  int blocks = (n_tokens + 3) / 4;
  score_kernel<<<blocks, 256, 0, stream>>>(hidden, W, bptr, scores, n_tokens);
  topk_mask_kernel<<<B, 256, 0, stream>>>(keep_ratio, scores, mask);
}

// Round 2
// 49.441 us; speedup vs baseline: 1.9400x; 1.9400x over previous
//
#include <hip/hip_runtime.h>

#define C_DIM 2048
#define T_TOKENS 4096

// Kernel 1: scores[n] = dot(hidden[n, :], W) + b0, one wave per token.
// f64 accumulation: score is ~exact, so the top-k boundary ordering is the
// true ordering (matched the np ref in round 0 -- do not perturb).
__global__ __launch_bounds__(256) void score_kernel(
    const float* __restrict__ hidden, const float* __restrict__ W,
    const float* __restrict__ bptr, float* __restrict__ scores, int n_tokens) {
  int wave = (int)((blockIdx.x * blockDim.x + threadIdx.x) >> 6);
  int lane = threadIdx.x & 63;
  if (wave >= n_tokens) return;
  const float* row = hidden + (size_t)wave * C_DIM;
  double acc = 0.0;
#pragma unroll
  for (int it = 0; it < C_DIM / (64 * 4); ++it) {
    int c = it * 256 + lane * 4;
    float4 h = *reinterpret_cast<const float4*>(row + c);
    float4 w = *reinterpret_cast<const float4*>(W + c);
    acc += (double)h.x * (double)w.x;
    acc += (double)h.y * (double)w.y;
    acc += (double)h.z * (double)w.z;
    acc += (double)h.w * (double)w.w;
  }
  for (int o = 32; o; o >>= 1) acc += __shfl_xor(acc, o);
  if (lane == 0) scores[wave] = (float)(acc + (double)bptr[0]);
}

// Kernel 2: per-batch variable-k top-k mask via 8-bit radix histogram descent.
// Thread tid owns tokens [tid*16, tid*16+16) -- contiguous, so the stable
// tie-break (smaller index first, matching argsort(argsort) rank) is a
// block-wide exclusive scan instead of an O(T) serial LDS walk.
__global__ __launch_bounds__(256) void topk_mask_kernel(
    const float* __restrict__ keep_ratio, const float* __restrict__ scores_all,
    float* __restrict__ mask) {
  const int b = blockIdx.x;
  const float* scores = scores_all + (size_t)b * T_TOKENS;
  __shared__ int s_hist[256];
  __shared__ int s_wave[4];
  __shared__ unsigned int s_sel;
  __shared__ int s_krem;
  const int tid = threadIdx.x;
  const int lane = tid & 63;
  const int wv = tid >> 6;

  // k = max(1, trunc(clip(kr, 0.1, 1.0) * T)); *4096 is a pure exponent
  // shift in fp32 -> exact, truncation matches jnp int32 cast bit-for-bit.
  float kf = fminf(fmaxf(keep_ratio[b], 0.1f), 1.0f);
  int k = (int)(kf * (float)T_TOKENS);
  if (k < 1) k = 1;

  // Load 16 contiguous scores -> order-preserving uint keys.
  unsigned int key[16];
  const float* base = scores + tid * 16;
#pragma unroll
  for (int i = 0; i < 16; i += 4) {
    float4 s4 = *reinterpret_cast<const float4*>(base + i);
    float ss[4] = {s4.x, s4.y, s4.z, s4.w};
#pragma unroll
    for (int j = 0; j < 4; ++j) {
      unsigned int u = __float_as_uint(ss[j]);
      key[i + j] = (u & 0x80000000u) ? ~u : (u | 0x80000000u);
    }
  }

  // 4-round byte radix descent: after round r, prefix holds the top (r+1)
  // bytes of the k-th largest key; krem = remaining quota within that prefix.
  unsigned int prefix = 0u;
  int krem = k;
#pragma unroll
  for (int round = 0; round < 4; ++round) {
    const int shift = 24 - 8 * round;
    const unsigned int pmask = (round == 0) ? 0u : (0xFFFFFFFFu << (shift + 8));

    s_hist[tid] = 0;
    __syncthreads();
#pragma unroll
    for (int i = 0; i < 16; ++i) {
      if ((key[i] & pmask) == prefix)
        atomicAdd(&s_hist[(key[i] >> shift) & 255], 1);
    }
    __syncthreads();

    // Inclusive suffix sum over 256 bins (bin index == tid).
    int v = s_hist[tid];
    int x = v;
#pragma unroll
    for (int off = 1; off < 64; off <<= 1) {
      int y = __shfl_down(x, off);
      if (lane + off < 64) x += y;
    }
    if (lane == 0) s_wave[wv] = x;
    __syncthreads();
    int add = 0;
    for (int w = wv + 1; w < 4; ++w) add += s_wave[w];
    const int suffix_incl = x + add;        // count of active keys in bins >= tid
    const int suffix_excl = suffix_incl - v; // bins > tid
    if (suffix_excl < krem && suffix_incl >= krem) {  // unique crossing bin
      s_sel = (unsigned int)tid;
      s_krem = krem - suffix_excl;
    }
    __syncthreads();
    prefix |= (s_sel << shift);
    krem = s_krem;
    __syncthreads();
  }
  // prefix = key of k-th largest; krem = # of ties (by index order) to keep.

  // Stable tie-break: exclusive count of equal keys at smaller token index.
  int cnt = 0;
#pragma unroll
  for (int i = 0; i < 16; ++i) cnt += (key[i] == prefix) ? 1 : 0;
  int inc = cnt;
#pragma unroll
  for (int off = 1; off < 64; off <<= 1) {
    int y = __shfl_up(inc, off);
    if (lane >= off) inc += y;
  }
  if (lane == 63) s_wave[wv] = inc;
  __syncthreads();
  int waveoff = 0;
  for (int w = 0; w < wv; ++w) waveoff += s_wave[w];
  int run = waveoff + inc - cnt;  // equals strictly before my first token

  float* mrow = mask + (size_t)b * T_TOKENS + tid * 16;
#pragma unroll
  for (int i = 0; i < 16; i += 4) {
    float4 m4;
    float mv[4];
#pragma unroll
    for (int j = 0; j < 4; ++j) {
      unsigned int kk = key[i + j];
      bool keep = (kk > prefix) || (kk == prefix && run < krem);
      run += (kk == prefix) ? 1 : 0;
      mv[j] = keep ? 1.0f : 0.0f;
    }
    m4.x = mv[0]; m4.y = mv[1]; m4.z = mv[2]; m4.w = mv[3];
    *reinterpret_cast<float4*>(mrow + i) = m4;
  }
}

extern "C" void kernel_launch(void* const* d_in, const int* in_sizes, int n_in,
                              void* d_out, int out_size, void* d_ws, size_t ws_size,
                              hipStream_t stream) {
  const float* hidden = (const float*)d_in[0];
  const float* keep_ratio = (const float*)d_in[1];
  const float* W = (const float*)d_in[2];
  const float* bptr = (const float*)d_in[3];

  const int B = in_sizes[1];
  const int n_tokens = in_sizes[0] / C_DIM;  // B*T = 32768

  float* out = (float*)d_out;
  float* mask = out;                       // output 0: [B, T] mask as 0/1 float
  float* scores = out + (size_t)n_tokens;  // output 1: [B, T] fp32 scores

  int blocks = (n_tokens + 3) / 4;
  score_kernel<<<blocks, 256, 0, stream>>>(hidden, W, bptr, scores, n_tokens);
  topk_mask_kernel<<<B, 256, 0, stream>>>(keep_ratio, scores, mask);
}